// Round 3
// baseline (662.575 us; speedup 1.0000x reference)
//
#include <hip/hip_runtime.h>
#include <hip/hip_bf16.h>

#define D_MODEL 1024
#define D_INNER 2048
#define NTOK    16384   // B*T = 4*4096
#define TLEN    4096
#define LN_EPS  1e-5f

typedef unsigned short u16;
typedef unsigned short u16x4 __attribute__((ext_vector_type(4)));
typedef unsigned short u16x8 __attribute__((ext_vector_type(8)));
typedef __bf16        bf16x8 __attribute__((ext_vector_type(8)));
typedef float         f32x4  __attribute__((ext_vector_type(4)));

__device__ __forceinline__ float b2f(u16 u) {
    union { float f; unsigned int i; } v; v.i = ((unsigned int)u) << 16; return v.f;
}
__device__ __forceinline__ u16 f2b(float f) {
    union { float f; unsigned int i; } v; v.f = f;
    unsigned int r = v.i + 0x7fffu + ((v.i >> 16) & 1u);  // RNE
    return (u16)(r >> 16);
}

// ---------------- fp32 -> bf16 bulk convert (weights) ----------------
__global__ __launch_bounds__(256) void cvt_f32_bf16(
    const float* __restrict__ src, u16* __restrict__ dst, int n)
{
    const int i = blockIdx.x * 256 + threadIdx.x;
    const int o = i * 4;
    if (o < n) {
        f32x4 v = *(const f32x4*)(src + o);
        u16x4 w;
#pragma unroll
        for (int j = 0; j < 4; j++) w[j] = f2b(v[j]);
        *(u16x4*)(dst + o) = w;
    }
}

// ---------------- LayerNorm (fp32 in, bf16 out): one block per row ----------------
__global__ __launch_bounds__(256) void ln_kernel(
    const float* __restrict__ x, const float* __restrict__ gamma,
    const float* __restrict__ beta, u16* __restrict__ xn)
{
    const int row = blockIdx.x;
    const int tid = threadIdx.x;
    const float* xr = x + (size_t)row * D_MODEL;
    const int c0 = tid * 4;

    f32x4 xv = *(const f32x4*)(xr + c0);
    float s = 0.f, s2 = 0.f;
#pragma unroll
    for (int i = 0; i < 4; i++) { s += xv[i]; s2 += xv[i] * xv[i]; }

#pragma unroll
    for (int off = 32; off > 0; off >>= 1) {
        s  += __shfl_down(s,  off);
        s2 += __shfl_down(s2, off);
    }
    __shared__ float red[8];
    const int wave = tid >> 6, lane = tid & 63;
    if (lane == 0) { red[wave] = s; red[4 + wave] = s2; }
    __syncthreads();
    const float ts  = red[0] + red[1] + red[2] + red[3];
    const float ts2 = red[4] + red[5] + red[6] + red[7];
    const float mu  = ts * (1.0f / D_MODEL);
    const float var = ts2 * (1.0f / D_MODEL) - mu * mu;
    const float inv = rsqrtf(var + LN_EPS);

    f32x4 gv = *(const f32x4*)(gamma + c0);
    f32x4 bv = *(const f32x4*)(beta + c0);
    u16x4 out;
#pragma unroll
    for (int i = 0; i < 4; i++)
        out[i] = f2b((xv[i] - mu) * inv * gv[i] + bv[i]);
    *(u16x4*)(xn + (size_t)row * D_MODEL + c0) = out;
}

// ---------------- GEMM C[M,N] = A[M,K] * Bt[N,K]^T (+fp32 residual) ----------------
// A, Bt are bf16. OUT_F32: C is float (with residual add); else C is bf16.
#define BM 128
#define BN 128
#define BK 64
#define LDS_S 72   // padded leading dim (elems)

template<bool OUT_F32>
__global__ __launch_bounds__(256) void gemm_bt(
    const u16* __restrict__ A, const u16* __restrict__ Bt,
    void* __restrict__ Cv, const float* __restrict__ Res,
    int M, int N, int K)
{
    __shared__ u16 As[BM * LDS_S];
    __shared__ u16 Bs[BN * LDS_S];

    const int tid  = threadIdx.x;
    const int bm   = blockIdx.x;
    const int bn   = blockIdx.y;
    const int wave = tid >> 6;
    const int lane = tid & 63;
    const int wm = wave >> 1, wn = wave & 1;
    const int lane15 = lane & 15, quad = lane >> 4;

    f32x4 acc[4][4] = {};

    const u16* Ag = A  + (size_t)bm * BM * K;
    const u16* Bg = Bt + (size_t)bn * BN * K;

    const int sr = tid >> 3;          // staging row 0..31 (+32 per pass)
    const int sc = (tid & 7) * 8;     // staging col chunk

    for (int kt = 0; kt < K; kt += BK) {
#pragma unroll
        for (int p = 0; p < 4; p++) {
            const int r = sr + p * 32;
            u16x8 va = *(const u16x8*)(Ag + (size_t)r * K + kt + sc);
            *(u16x8*)(&As[r * LDS_S + sc]) = va;
            u16x8 vb = *(const u16x8*)(Bg + (size_t)r * K + kt + sc);
            *(u16x8*)(&Bs[r * LDS_S + sc]) = vb;
        }
        __syncthreads();

#pragma unroll
        for (int kk = 0; kk < BK; kk += 32) {
            bf16x8 af[4], bfr[4];
#pragma unroll
            for (int t = 0; t < 4; t++) {
                af[t]  = __builtin_bit_cast(bf16x8,
                    *(const u16x8*)(&As[(wm * 64 + t * 16 + lane15) * LDS_S + kk + quad * 8]));
                bfr[t] = __builtin_bit_cast(bf16x8,
                    *(const u16x8*)(&Bs[(wn * 64 + t * 16 + lane15) * LDS_S + kk + quad * 8]));
            }
#pragma unroll
            for (int tm = 0; tm < 4; tm++)
#pragma unroll
                for (int tn = 0; tn < 4; tn++)
                    acc[tm][tn] = __builtin_amdgcn_mfma_f32_16x16x32_bf16(
                        af[tm], bfr[tn], acc[tm][tn], 0, 0, 0);
        }
        __syncthreads();
    }

    // Epilogue: C[row = quad*4+i][col = lane15] per 16x16 subtile
    const int m0 = bm * BM + wm * 64 + quad * 4;
    const int n0 = bn * BN + wn * 64 + lane15;
#pragma unroll
    for (int tm = 0; tm < 4; tm++) {
#pragma unroll
        for (int tn = 0; tn < 4; tn++) {
#pragma unroll
            for (int i = 0; i < 4; i++) {
                const int r  = m0 + tm * 16 + i;
                const int cc = n0 + tn * 16;
                const size_t idx = (size_t)r * N + cc;
                float v = acc[tm][tn][i];
                if (OUT_F32) {
                    ((float*)Cv)[idx] = v + Res[idx];
                } else {
                    ((u16*)Cv)[idx] = f2b(v);
                }
            }
        }
    }
}

// ---------------- causal depthwise conv (d_conv=4) + silu(x)*silu(z) ----------------
// xz: [rows, 4096] bf16; cols [0,2048)=x_part, [2048,4096)=z. Chunk boundaries
// are batch boundaries so t = row & (TLEN-1) is the within-sequence position.
__global__ __launch_bounds__(256) void conv_gate(
    const u16* __restrict__ xz, const float* __restrict__ conv_w,
    const float* __restrict__ conv_b, u16* __restrict__ y)
{
    const int gid = blockIdx.x * 256 + threadIdx.x;
    const int c8  = gid & 255;            // channel-group (8 channels)
    const int row = gid >> 8;             // token index (chunk-local)
    const int c   = c8 * 8;
    const int t   = row & (TLEN - 1);

    float acc[8];
#pragma unroll
    for (int u = 0; u < 8; u++) acc[u] = conv_b[c + u];

#pragma unroll
    for (int j = 0; j < 4; j++) {         // tap j multiplies x[t-3+j]
        const int dt = 3 - j;
        if (t >= dt) {
            u16x8 xv = *(const u16x8*)(xz + (size_t)(row - dt) * 4096 + c);
#pragma unroll
            for (int u = 0; u < 8; u++)
                acc[u] += b2f(xv[u]) * conv_w[(c + u) * 4 + j];
        }
    }

    u16x8 zv = *(const u16x8*)(xz + (size_t)row * 4096 + 2048 + c);
    u16x8 out;
#pragma unroll
    for (int u = 0; u < 8; u++) {
        const float a = acc[u];
        const float z = b2f(zv[u]);
        const float sa = a / (1.0f + __expf(-a));
        const float sz = z / (1.0f + __expf(-z));
        out[u] = f2b(sa * sz);
    }
    *(u16x8*)(y + (size_t)row * (size_t)D_INNER + c) = out;
}

extern "C" void kernel_launch(void* const* d_in, const int* in_sizes, int n_in,
                              void* d_out, int out_size, void* d_ws, size_t ws_size,
                              hipStream_t stream)
{
    const float* x      = (const float*)d_in[0];
    const float* gamma  = (const float*)d_in[1];
    const float* beta   = (const float*)d_in[2];
    const float* W_in   = (const float*)d_in[3];  // [4096, 1024] fp32
    const float* conv_w = (const float*)d_in[4];  // [2048, 1, 4] fp32
    const float* conv_b = (const float*)d_in[5];  // [2048] fp32
    const float* W_out  = (const float*)d_in[6];  // [1024, 2048] fp32
    float* out = (float*)d_out;

    const int nWin  = 4096 * 1024;   // 4.19M elems
    const int nWout = 1024 * 2048;   // 2.10M elems

    u16* wbin  = (u16*)d_ws;                 // bf16 W_in
    u16* wbout = wbin + nWin;                // bf16 W_out
    u16* base  = wbout + nWout;

    // Workspace-adaptive chunking (whole batches -> conv halo never crosses).
    // Per token-row scratch: xn 1024 + xz 4096 + y 2048 bf16 = 14336 B.
    const size_t wbytes = (size_t)(nWin + nWout) * sizeof(u16);
    const size_t perRow = (size_t)(D_MODEL + 4096 + D_INNER) * sizeof(u16);
    int NC = 4;                                                    // 71.3 MB
    if (ws_size >= wbytes + (size_t)NTOK * perRow)          NC = 1; // 247.5 MB
    else if (ws_size >= wbytes + (size_t)(NTOK/2) * perRow) NC = 2; // 130.1 MB
    const int RC = NTOK / NC;

    u16* xn = base;                               // RC*1024
    u16* xz = xn + (size_t)RC * D_MODEL;          // RC*4096
    u16* y  = xz + (size_t)RC * 4096;             // RC*2048

    // 0. weights fp32 -> bf16 (every call; same work each call)
    cvt_f32_bf16<<<(nWin / 4 + 255) / 256, 256, 0, stream>>>(W_in, wbin, nWin);
    cvt_f32_bf16<<<(nWout / 4 + 255) / 256, 256, 0, stream>>>(W_out, wbout, nWout);

    for (int c = 0; c < NC; c++) {
        const float* xc   = x   + (size_t)c * RC * D_MODEL;
        float*       outc = out + (size_t)c * RC * D_MODEL;

        // 1. LayerNorm
        ln_kernel<<<RC, 256, 0, stream>>>(xc, gamma, beta, xn);

        // 2. in_proj: xz[RC,4096] = xn[RC,1024] @ W_in^T  (bf16 out)
        dim3 g1(RC / BM, 4096 / BN);
        gemm_bt<false><<<g1, 256, 0, stream>>>(xn, wbin, xz, nullptr,
                                               RC, 2 * D_INNER, D_MODEL);

        // 3. causal depthwise conv + silu gating
        conv_gate<<<RC, 256, 0, stream>>>(xz, conv_w, conv_b, y);

        // 4. out_proj + residual: out[RC,1024] = x + y[RC,2048] @ W_out^T (fp32 out)
        dim3 g2(RC / BM, D_MODEL / BN);
        gemm_bt<true><<<g2, 256, 0, stream>>>(y, wbout, outc, xc,
                                              RC, D_MODEL, D_INNER);
    }
}

// Round 4
// 531.544 us; speedup vs baseline: 1.2465x; 1.2465x over previous
//
#include <hip/hip_runtime.h>
#include <hip/hip_bf16.h>

#define D_MODEL 1024
#define D_INNER 2048
#define NTOK    16384   // B*T = 4*4096
#define TLEN    4096
#define LN_EPS  1e-5f

typedef unsigned short u16;
typedef unsigned short u16x4 __attribute__((ext_vector_type(4)));
typedef unsigned short u16x8 __attribute__((ext_vector_type(8)));
typedef __bf16        bf16x8 __attribute__((ext_vector_type(8)));
typedef float         f32x4  __attribute__((ext_vector_type(4)));

__device__ __forceinline__ float b2f(u16 u) {
    union { float f; unsigned int i; } v; v.i = ((unsigned int)u) << 16; return v.f;
}
__device__ __forceinline__ u16 f2b(float f) {
    union { float f; unsigned int i; } v; v.f = f;
    unsigned int r = v.i + 0x7fffu + ((v.i >> 16) & 1u);  // RNE
    return (u16)(r >> 16);
}

// async global->LDS, 16B per lane. LDS dest = wave-uniform base + lane*16.
__device__ __forceinline__ void gld_lds16(const u16* g, u16* l) {
    __builtin_amdgcn_global_load_lds(
        (const __attribute__((address_space(1))) void*)g,
        (__attribute__((address_space(3))) void*)l, 16, 0, 0);
}

// ---------------- fp32 -> bf16 bulk convert (weights) ----------------
__global__ __launch_bounds__(256) void cvt_f32_bf16(
    const float* __restrict__ src, u16* __restrict__ dst, int n)
{
    const int i = blockIdx.x * 256 + threadIdx.x;
    const int o = i * 4;
    if (o < n) {
        f32x4 v = *(const f32x4*)(src + o);
        u16x4 w;
#pragma unroll
        for (int j = 0; j < 4; j++) w[j] = f2b(v[j]);
        *(u16x4*)(dst + o) = w;
    }
}

// ---------------- conv_w [2048][4] -> wt [4][2048] fp32 transpose ----------------
__global__ __launch_bounds__(256) void cvt_convw(
    const float* __restrict__ w, float* __restrict__ wt)
{
    const int i = blockIdx.x * 256 + threadIdx.x;   // 0..8191
    const int ch = i >> 2, j = i & 3;
    wt[j * D_INNER + ch] = w[i];
}

// ---------------- LayerNorm (fp32 in, bf16 out): one block per row ----------------
__global__ __launch_bounds__(256) void ln_kernel(
    const float* __restrict__ x, const float* __restrict__ gamma,
    const float* __restrict__ beta, u16* __restrict__ xn)
{
    const int row = blockIdx.x;
    const int tid = threadIdx.x;
    const float* xr = x + (size_t)row * D_MODEL;
    const int c0 = tid * 4;

    f32x4 xv = *(const f32x4*)(xr + c0);
    float s = 0.f, s2 = 0.f;
#pragma unroll
    for (int i = 0; i < 4; i++) { s += xv[i]; s2 += xv[i] * xv[i]; }

#pragma unroll
    for (int off = 32; off > 0; off >>= 1) {
        s  += __shfl_down(s,  off);
        s2 += __shfl_down(s2, off);
    }
    __shared__ float red[8];
    const int wave = tid >> 6, lane = tid & 63;
    if (lane == 0) { red[wave] = s; red[4 + wave] = s2; }
    __syncthreads();
    const float ts  = red[0] + red[1] + red[2] + red[3];
    const float ts2 = red[4] + red[5] + red[6] + red[7];
    const float mu  = ts * (1.0f / D_MODEL);
    const float var = ts2 * (1.0f / D_MODEL) - mu * mu;
    const float inv = rsqrtf(var + LN_EPS);

    f32x4 gv = *(const f32x4*)(gamma + c0);
    f32x4 bv = *(const f32x4*)(beta + c0);
    u16x4 out;
#pragma unroll
    for (int i = 0; i < 4; i++)
        out[i] = f2b((xv[i] - mu) * inv * gv[i] + bv[i]);
    *(u16x4*)(xn + (size_t)row * D_MODEL + c0) = out;
}

// ---------------- GEMM C[M,N] = A[M,K] * Bt[N,K]^T (+fp32 residual) ----------------
// 128x128 tile, BK=64, 4 waves 2x2 (64x64 each). m97-style global_load_lds
// width-16 staging: LDS unpadded stride 64 (padding breaks the lane mapping).
template<bool OUT_F32>
__global__ __launch_bounds__(256) void gemm_bt(
    const u16* __restrict__ A, const u16* __restrict__ Bt,
    void* __restrict__ Cv, const float* __restrict__ Res,
    int M, int N, int K)
{
    __shared__ u16 As[128 * 64];
    __shared__ u16 Bs[128 * 64];

    const int tid  = threadIdx.x;
    const int bm   = blockIdx.x;
    const int bn   = blockIdx.y;
    const int wave = tid >> 6;
    const int lane = tid & 63;
    const int wm = wave >> 1, wn = wave & 1;
    const int lane15 = lane & 15, quad = lane >> 4;

    f32x4 acc[4][4] = {};

    const u16* Ag = A  + (size_t)bm * 128 * K;
    const u16* Bg = Bt + (size_t)bn * 128 * K;

    const int lrow = lane >> 3;        // 0..7  (row within the wave's 8-row slab)
    const int lcol = (lane & 7) * 8;   // element offset (16B chunk)

    for (int kt = 0; kt < K; kt += 64) {
#pragma unroll
        for (int p = 0; p < 4; p++) {
            const int r = p * 32 + wave * 8;   // wave-uniform slab base
            gld_lds16(Ag + (size_t)(r + lrow) * K + kt + lcol, &As[r * 64]);
            gld_lds16(Bg + (size_t)(r + lrow) * K + kt + lcol, &Bs[r * 64]);
        }
        __syncthreads();

#pragma unroll
        for (int kk = 0; kk < 64; kk += 32) {
            bf16x8 af[4], bfr[4];
#pragma unroll
            for (int t = 0; t < 4; t++) {
                af[t]  = __builtin_bit_cast(bf16x8,
                    *(const u16x8*)(&As[(wm * 64 + t * 16 + lane15) * 64 + kk + quad * 8]));
                bfr[t] = __builtin_bit_cast(bf16x8,
                    *(const u16x8*)(&Bs[(wn * 64 + t * 16 + lane15) * 64 + kk + quad * 8]));
            }
#pragma unroll
            for (int tm = 0; tm < 4; tm++)
#pragma unroll
                for (int tn = 0; tn < 4; tn++)
                    acc[tm][tn] = __builtin_amdgcn_mfma_f32_16x16x32_bf16(
                        af[tm], bfr[tn], acc[tm][tn], 0, 0, 0);
        }
        __syncthreads();
    }

    // Epilogue: C[row = quad*4+i][col = lane15] per 16x16 subtile
    const int m0 = bm * 128 + wm * 64 + quad * 4;
    const int n0 = bn * 128 + wn * 64 + lane15;
#pragma unroll
    for (int tm = 0; tm < 4; tm++) {
#pragma unroll
        for (int tn = 0; tn < 4; tn++) {
#pragma unroll
            for (int i = 0; i < 4; i++) {
                const int r  = m0 + tm * 16 + i;
                const int cc = n0 + tn * 16;
                const size_t idx = (size_t)r * N + cc;
                float v = acc[tm][tn][i];
                if (OUT_F32) {
                    ((float*)Cv)[idx] = v + Res[idx];
                } else {
                    ((u16*)Cv)[idx] = f2b(v);
                }
            }
        }
    }
}

// ---------------- causal depthwise conv (d_conv=4) + silu(x)*silu(z) ----------------
// 4 tokens per thread (same sequence: 4096%4==0 so no boundary crossing).
// wt is the transposed [4][2048] fp32 weight -> coalesced loads.
__global__ __launch_bounds__(256) void conv_gate4(
    const u16* __restrict__ xz, const float* __restrict__ wt,
    const float* __restrict__ conv_b, u16* __restrict__ y)
{
    const int tid  = threadIdx.x;
    const int row0 = blockIdx.x * 4;          // first token row of this block
    const int c    = tid * 8;                 // channel base
    const int t0   = row0 & (TLEN - 1);       // within-sequence position

    float w[4][8];
#pragma unroll
    for (int j = 0; j < 4; j++) {
        f32x4 a = *(const f32x4*)(wt + j * D_INNER + c);
        f32x4 b = *(const f32x4*)(wt + j * D_INNER + c + 4);
#pragma unroll
        for (int u = 0; u < 4; u++) { w[j][u] = a[u]; w[j][4 + u] = b[u]; }
    }
    float bias[8];
    {
        f32x4 a = *(const f32x4*)(conv_b + c);
        f32x4 b = *(const f32x4*)(conv_b + c + 4);
#pragma unroll
        for (int u = 0; u < 4; u++) { bias[u] = a[u]; bias[4 + u] = b[u]; }
    }

    // x_part rows row0-3 .. row0+3  (t0 is a multiple of 4: t0==0 means the
    // three look-back rows are all pad-zero; else all valid — uniform branch)
    u16x8 xv[7];
    if (t0 != 0) {
#pragma unroll
        for (int k = 0; k < 3; k++)
            xv[k] = *(const u16x8*)(xz + (size_t)(row0 - 3 + k) * 4096 + c);
    } else {
#pragma unroll
        for (int k = 0; k < 3; k++) xv[k] = (u16x8)0;
    }
#pragma unroll
    for (int k = 3; k < 7; k++)
        xv[k] = *(const u16x8*)(xz + (size_t)(row0 - 3 + k) * 4096 + c);

#pragma unroll
    for (int i = 0; i < 3 + 1; i++) {         // output tokens row0+i
        float acc[8];
#pragma unroll
        for (int u = 0; u < 8; u++) acc[u] = bias[u];
#pragma unroll
        for (int j = 0; j < 4; j++)           // tap j uses x[t-3+j] = xv[i+j]
#pragma unroll
            for (int u = 0; u < 8; u++)
                acc[u] += b2f(xv[i + j][u]) * w[j][u];

        u16x8 zv = *(const u16x8*)(xz + (size_t)(row0 + i) * 4096 + 2048 + c);
        u16x8 out;
#pragma unroll
        for (int u = 0; u < 8; u++) {
            const float a = acc[u];
            const float z = b2f(zv[u]);
            const float sa = a / (1.0f + __expf(-a));
            const float sz = z / (1.0f + __expf(-z));
            out[u] = f2b(sa * sz);
        }
        *(u16x8*)(y + (size_t)(row0 + i) * (size_t)D_INNER + c) = out;
    }
}

extern "C" void kernel_launch(void* const* d_in, const int* in_sizes, int n_in,
                              void* d_out, int out_size, void* d_ws, size_t ws_size,
                              hipStream_t stream)
{
    const float* x      = (const float*)d_in[0];
    const float* gamma  = (const float*)d_in[1];
    const float* beta   = (const float*)d_in[2];
    const float* W_in   = (const float*)d_in[3];  // [4096, 1024] fp32
    const float* conv_w = (const float*)d_in[4];  // [2048, 1, 4] fp32
    const float* conv_b = (const float*)d_in[5];  // [2048] fp32
    const float* W_out  = (const float*)d_in[6];  // [1024, 2048] fp32
    float* out = (float*)d_out;

    const int nWin  = 4096 * 1024;
    const int nWout = 1024 * 2048;
    const int nWc   = D_INNER * 4;            // 8192

    u16*   wbin  = (u16*)d_ws;                // bf16 W_in
    u16*   wbout = wbin + nWin;               // bf16 W_out
    float* wt    = (float*)(wbout + nWout);   // fp32 [4][2048] conv weights
    u16*   base  = (u16*)(wt + nWc);

    // Workspace-adaptive chunking (whole batches -> conv halo never crosses).
    const size_t wbytes = (size_t)(nWin + nWout) * sizeof(u16) + nWc * sizeof(float);
    const size_t perRow = (size_t)(D_MODEL + 4096 + D_INNER) * sizeof(u16);
    int NC = 4;
    if (ws_size >= wbytes + (size_t)NTOK * perRow)          NC = 1;
    else if (ws_size >= wbytes + (size_t)(NTOK/2) * perRow) NC = 2;
    const int RC = NTOK / NC;

    u16* xn = base;                               // RC*1024
    u16* xz = xn + (size_t)RC * D_MODEL;          // RC*4096
    u16* y  = xz + (size_t)RC * 4096;             // RC*2048

    // 0. weight preprocessing (same work every call)
    cvt_f32_bf16<<<(nWin / 4 + 255) / 256, 256, 0, stream>>>(W_in, wbin, nWin);
    cvt_f32_bf16<<<(nWout / 4 + 255) / 256, 256, 0, stream>>>(W_out, wbout, nWout);
    cvt_convw<<<nWc / 256, 256, 0, stream>>>(conv_w, wt);

    for (int c = 0; c < NC; c++) {
        const float* xc   = x   + (size_t)c * RC * D_MODEL;
        float*       outc = out + (size_t)c * RC * D_MODEL;

        // 1. LayerNorm
        ln_kernel<<<RC, 256, 0, stream>>>(xc, gamma, beta, xn);

        // 2. in_proj: xz[RC,4096] = xn[RC,1024] @ W_in^T  (bf16 out)
        dim3 g1(RC / 128, 4096 / 128);
        gemm_bt<false><<<g1, 256, 0, stream>>>(xn, wbin, xz, nullptr,
                                               RC, 2 * D_INNER, D_MODEL);

        // 3. causal depthwise conv + silu gating (4 tokens/thread)
        conv_gate4<<<RC / 4, 256, 0, stream>>>(xz, wt, conv_b, y);

        // 4. out_proj + residual: out[RC,1024] = x + y[RC,2048] @ W_out^T (fp32 out)
        dim3 g2(RC / 128, D_MODEL / 128);
        gemm_bt<true><<<g2, 256, 0, stream>>>(y, wbout, outc, xc,
                                              RC, D_MODEL, D_INNER);
    }
}

// Round 5
// 471.819 us; speedup vs baseline: 1.4043x; 1.1266x over previous
//
#include <hip/hip_runtime.h>
#include <hip/hip_bf16.h>

#define D_MODEL 1024
#define D_INNER 2048
#define NTOK    16384   // B*T = 4*4096
#define TLEN    4096
#define LN_EPS  1e-5f

typedef unsigned short u16;
typedef unsigned short u16x4 __attribute__((ext_vector_type(4)));
typedef unsigned short u16x8 __attribute__((ext_vector_type(8)));
typedef __bf16        bf16x8 __attribute__((ext_vector_type(8)));
typedef float         f32x4  __attribute__((ext_vector_type(4)));

__device__ __forceinline__ float b2f(u16 u) {
    union { float f; unsigned int i; } v; v.i = ((unsigned int)u) << 16; return v.f;
}
__device__ __forceinline__ u16 f2b(float f) {
    union { float f; unsigned int i; } v; v.f = f;
    unsigned int r = v.i + 0x7fffu + ((v.i >> 16) & 1u);  // RNE
    return (u16)(r >> 16);
}

// async global->LDS, 16B per lane. LDS dest = wave-uniform base + lane*16.
__device__ __forceinline__ void gld_lds16(const u16* g, u16* l) {
    __builtin_amdgcn_global_load_lds(
        (const __attribute__((address_space(1))) void*)g,
        (__attribute__((address_space(3))) void*)l, 16, 0, 0);
}

// ---------------- fp32 -> bf16 bulk convert (weights) ----------------
__global__ __launch_bounds__(256) void cvt_f32_bf16(
    const float* __restrict__ src, u16* __restrict__ dst, int n)
{
    const int i = blockIdx.x * 256 + threadIdx.x;
    const int o = i * 4;
    if (o < n) {
        f32x4 v = *(const f32x4*)(src + o);
        u16x4 w;
#pragma unroll
        for (int j = 0; j < 4; j++) w[j] = f2b(v[j]);
        *(u16x4*)(dst + o) = w;
    }
}

// ---------------- conv_w [2048][4] -> wt [4][2048] fp32 transpose ----------------
__global__ __launch_bounds__(256) void cvt_convw(
    const float* __restrict__ w, float* __restrict__ wt)
{
    const int i = blockIdx.x * 256 + threadIdx.x;   // 0..8191
    const int ch = i >> 2, j = i & 3;
    wt[j * D_INNER + ch] = w[i];
}

// ---------------- LayerNorm (fp32 in, bf16 out): one block per row ----------------
__global__ __launch_bounds__(256) void ln_kernel(
    const float* __restrict__ x, const float* __restrict__ gamma,
    const float* __restrict__ beta, u16* __restrict__ xn)
{
    const int row = blockIdx.x;
    const int tid = threadIdx.x;
    const float* xr = x + (size_t)row * D_MODEL;
    const int c0 = tid * 4;

    f32x4 xv = *(const f32x4*)(xr + c0);
    float s = 0.f, s2 = 0.f;
#pragma unroll
    for (int i = 0; i < 4; i++) { s += xv[i]; s2 += xv[i] * xv[i]; }

#pragma unroll
    for (int off = 32; off > 0; off >>= 1) {
        s  += __shfl_down(s,  off);
        s2 += __shfl_down(s2, off);
    }
    __shared__ float red[8];
    const int wave = tid >> 6, lane = tid & 63;
    if (lane == 0) { red[wave] = s; red[4 + wave] = s2; }
    __syncthreads();
    const float ts  = red[0] + red[1] + red[2] + red[3];
    const float ts2 = red[4] + red[5] + red[6] + red[7];
    const float mu  = ts * (1.0f / D_MODEL);
    const float var = ts2 * (1.0f / D_MODEL) - mu * mu;
    const float inv = rsqrtf(var + LN_EPS);

    f32x4 gv = *(const f32x4*)(gamma + c0);
    f32x4 bv = *(const f32x4*)(beta + c0);
    u16x4 out;
#pragma unroll
    for (int i = 0; i < 4; i++)
        out[i] = f2b((xv[i] - mu) * inv * gv[i] + bv[i]);
    *(u16x4*)(xn + (size_t)row * D_MODEL + c0) = out;
}

// ---------------- GEMM C[M,N] = A[M,K] * Bt[N,K]^T (+fp32 residual) ----------------
// 128x128 tile, BK=64, 4 waves 2x2 (64x64 each). global_load_lds width-16
// staging with XOR-swizzled LDS layout: LDS[row][chunk] = G[row][chunk^(row&7)]
// (swizzle applied on the SOURCE address since the LDS dest is lane-pinned).
// Fragment reads then place 8 consecutive lanes on 8 distinct 16B chunks
// -> all 32 banks covered -> conflict-free ds_read_b128.
template<bool OUT_F32>
__global__ __launch_bounds__(256) void gemm_bt(
    const u16* __restrict__ A, const u16* __restrict__ Bt,
    void* __restrict__ Cv, const float* __restrict__ Res,
    int M, int N, int K)
{
    __shared__ u16 As[128 * 64];
    __shared__ u16 Bs[128 * 64];

    const int tid  = threadIdx.x;
    const int bm   = blockIdx.x;
    const int bn   = blockIdx.y;
    const int wave = tid >> 6;
    const int lane = tid & 63;
    const int wm = wave >> 1, wn = wave & 1;
    const int lane15 = lane & 15, quad = lane >> 4;

    f32x4 acc[4][4] = {};

    const u16* Ag = A  + (size_t)bm * 128 * K;
    const u16* Bg = Bt + (size_t)bn * 128 * K;

    const int lrow = lane >> 3;                   // 0..7 row within 8-row slab
    const int lcol = ((lane & 7) ^ lrow) * 8;     // swizzled source chunk

    const int sw = lane15 & 7;                    // fragment-read swizzle key

    for (int kt = 0; kt < K; kt += 64) {
#pragma unroll
        for (int p = 0; p < 4; p++) {
            const int r = p * 32 + wave * 8;      // wave-uniform slab base
            gld_lds16(Ag + (size_t)(r + lrow) * K + kt + lcol, &As[r * 64]);
            gld_lds16(Bg + (size_t)(r + lrow) * K + kt + lcol, &Bs[r * 64]);
        }
        __syncthreads();

#pragma unroll
        for (int kk = 0; kk < 64; kk += 32) {
            const int chunk = (((kk >> 3) + quad) ^ sw) * 8;
            bf16x8 af[4], bfr[4];
#pragma unroll
            for (int t = 0; t < 4; t++) {
                af[t]  = __builtin_bit_cast(bf16x8,
                    *(const u16x8*)(&As[(wm * 64 + t * 16 + lane15) * 64 + chunk]));
                bfr[t] = __builtin_bit_cast(bf16x8,
                    *(const u16x8*)(&Bs[(wn * 64 + t * 16 + lane15) * 64 + chunk]));
            }
#pragma unroll
            for (int tm = 0; tm < 4; tm++)
#pragma unroll
                for (int tn = 0; tn < 4; tn++)
                    acc[tm][tn] = __builtin_amdgcn_mfma_f32_16x16x32_bf16(
                        af[tm], bfr[tn], acc[tm][tn], 0, 0, 0);
        }
        __syncthreads();
    }

    // Epilogue: C[row = quad*4+i][col = lane15] per 16x16 subtile
    const int m0 = bm * 128 + wm * 64 + quad * 4;
    const int n0 = bn * 128 + wn * 64 + lane15;
#pragma unroll
    for (int tm = 0; tm < 4; tm++) {
#pragma unroll
        for (int tn = 0; tn < 4; tn++) {
#pragma unroll
            for (int i = 0; i < 4; i++) {
                const int r  = m0 + tm * 16 + i;
                const int cc = n0 + tn * 16;
                const size_t idx = (size_t)r * N + cc;
                float v = acc[tm][tn][i];
                if (OUT_F32) {
                    ((float*)Cv)[idx] = v + Res[idx];
                } else {
                    ((u16*)Cv)[idx] = f2b(v);
                }
            }
        }
    }
}

// ---------------- causal depthwise conv (d_conv=4) + silu(x)*silu(z) ----------------
// 4 tokens per thread; wt is transposed [4][2048] fp32 -> coalesced loads.
__global__ __launch_bounds__(256) void conv_gate4(
    const u16* __restrict__ xz, const float* __restrict__ wt,
    const float* __restrict__ conv_b, u16* __restrict__ y)
{
    const int tid  = threadIdx.x;
    const int row0 = blockIdx.x * 4;          // first token row of this block
    const int c    = tid * 8;                 // channel base
    const int t0   = row0 & (TLEN - 1);       // within-sequence position

    float w[4][8];
#pragma unroll
    for (int j = 0; j < 4; j++) {
        f32x4 a = *(const f32x4*)(wt + j * D_INNER + c);
        f32x4 b = *(const f32x4*)(wt + j * D_INNER + c + 4);
#pragma unroll
        for (int u = 0; u < 4; u++) { w[j][u] = a[u]; w[j][4 + u] = b[u]; }
    }
    float bias[8];
    {
        f32x4 a = *(const f32x4*)(conv_b + c);
        f32x4 b = *(const f32x4*)(conv_b + c + 4);
#pragma unroll
        for (int u = 0; u < 4; u++) { bias[u] = a[u]; bias[4 + u] = b[u]; }
    }

    u16x8 xv[7];
    if (t0 != 0) {
#pragma unroll
        for (int k = 0; k < 3; k++)
            xv[k] = *(const u16x8*)(xz + (size_t)(row0 - 3 + k) * 4096 + c);
    } else {
#pragma unroll
        for (int k = 0; k < 3; k++) xv[k] = (u16x8)0;
    }
#pragma unroll
    for (int k = 3; k < 7; k++)
        xv[k] = *(const u16x8*)(xz + (size_t)(row0 - 3 + k) * 4096 + c);

#pragma unroll
    for (int i = 0; i < 4; i++) {             // output tokens row0+i
        float acc[8];
#pragma unroll
        for (int u = 0; u < 8; u++) acc[u] = bias[u];
#pragma unroll
        for (int j = 0; j < 4; j++)           // tap j uses x[t-3+j] = xv[i+j]
#pragma unroll
            for (int u = 0; u < 8; u++)
                acc[u] += b2f(xv[i + j][u]) * w[j][u];

        u16x8 zv = *(const u16x8*)(xz + (size_t)(row0 + i) * 4096 + 2048 + c);
        u16x8 out;
#pragma unroll
        for (int u = 0; u < 8; u++) {
            const float a = acc[u];
            const float z = b2f(zv[u]);
            const float sa = a / (1.0f + __expf(-a));
            const float sz = z / (1.0f + __expf(-z));
            out[u] = f2b(sa * sz);
        }
        *(u16x8*)(y + (size_t)(row0 + i) * (size_t)D_INNER + c) = out;
    }
}

extern "C" void kernel_launch(void* const* d_in, const int* in_sizes, int n_in,
                              void* d_out, int out_size, void* d_ws, size_t ws_size,
                              hipStream_t stream)
{
    const float* x      = (const float*)d_in[0];
    const float* gamma  = (const float*)d_in[1];
    const float* beta   = (const float*)d_in[2];
    const float* W_in   = (const float*)d_in[3];  // [4096, 1024] fp32
    const float* conv_w = (const float*)d_in[4];  // [2048, 1, 4] fp32
    const float* conv_b = (const float*)d_in[5];  // [2048] fp32
    const float* W_out  = (const float*)d_in[6];  // [1024, 2048] fp32
    float* out = (float*)d_out;

    const int nWin  = 4096 * 1024;
    const int nWout = 1024 * 2048;
    const int nWc   = D_INNER * 4;            // 8192

    u16*   wbin  = (u16*)d_ws;                // bf16 W_in
    u16*   wbout = wbin + nWin;               // bf16 W_out
    float* wt    = (float*)(wbout + nWout);   // fp32 [4][2048] conv weights
    u16*   base  = (u16*)(wt + nWc);

    // Workspace-adaptive chunking (whole batches -> conv halo never crosses).
    const size_t wbytes = (size_t)(nWin + nWout) * sizeof(u16) + nWc * sizeof(float);
    const size_t perRow = (size_t)(D_MODEL + 4096 + D_INNER) * sizeof(u16);
    int NC = 4;
    if (ws_size >= wbytes + (size_t)NTOK * perRow)          NC = 1;
    else if (ws_size >= wbytes + (size_t)(NTOK/2) * perRow) NC = 2;
    const int RC = NTOK / NC;

    u16* xn = base;                               // RC*1024
    u16* xz = xn + (size_t)RC * D_MODEL;          // RC*4096
    u16* y  = xz + (size_t)RC * 4096;             // RC*2048

    // 0. weight preprocessing (same work every call)
    cvt_f32_bf16<<<(nWin / 4 + 255) / 256, 256, 0, stream>>>(W_in, wbin, nWin);
    cvt_f32_bf16<<<(nWout / 4 + 255) / 256, 256, 0, stream>>>(W_out, wbout, nWout);
    cvt_convw<<<nWc / 256, 256, 0, stream>>>(conv_w, wt);

    for (int c = 0; c < NC; c++) {
        const float* xc   = x   + (size_t)c * RC * D_MODEL;
        float*       outc = out + (size_t)c * RC * D_MODEL;

        // 1. LayerNorm
        ln_kernel<<<RC, 256, 0, stream>>>(xc, gamma, beta, xn);

        // 2. in_proj: xz[RC,4096] = xn[RC,1024] @ W_in^T  (bf16 out)
        dim3 g1(RC / 128, 4096 / 128);
        gemm_bt<false><<<g1, 256, 0, stream>>>(xn, wbin, xz, nullptr,
                                               RC, 2 * D_INNER, D_MODEL);

        // 3. causal depthwise conv + silu gating (4 tokens/thread)
        conv_gate4<<<RC / 4, 256, 0, stream>>>(xz, wt, conv_b, y);

        // 4. out_proj + residual: out[RC,1024] = x + y[RC,2048] @ W_out^T (fp32 out)
        dim3 g2(RC / 128, D_MODEL / 128);
        gemm_bt<true><<<g2, 256, 0, stream>>>(y, wbout, outc, xc,
                                              RC, D_MODEL, D_INNER);
    }
}